// Round 6
// baseline (192.642 us; speedup 1.0000x reference)
//
#include <hip/hip_runtime.h>
#include <hip/hip_bf16.h>
#include <stdint.h>

// Problem constants
#define BB 16
#define NPTS 100000
#define NBOX 64
#define KTOP 2048
#define THRF 0.2f            // (float)(8*0.01*2.5)
// band around 0.2^2 for exact-path fallback; fast path error bound ~5e-6
#define C_LO 0.039984f
#define C_HI 0.040016f

#define HSLICES 98
#define SLICE_PTS 1024
#define LIST_CAP 4096        // candidates expected ~2275 +/- 47 (>=25 sigma margin)

// Workspace layout (uint32 words). Only CTR needs zeroing (64 B memset).
#define VALS_OFF  0                                   // BB*HSLICES*1024 bucketed values
#define HISTG_OFF (BB * HSLICES * 1024)               // BB*HSLICES*256 per-slice hist
#define PREFG_OFF (HISTG_OFF + BB * HSLICES * 256)    // BB*HSLICES*256 per-slice excl prefix
#define STATE_OFF (PREFG_OFF + BB * HSLICES * 256)    // BB*2 {T_bits, Istar}
#define CTR_OFF   (STATE_OFF + BB * 2)                // BB done-counters (memset to 0)

__device__ __forceinline__ uint32_t fmap(float f) {
    uint32_t b = __float_as_uint(f);
    return (b & 0x80000000u) ? ~b : (b | 0x80000000u);
}

// ---------- K1: per-slice LDS counting sort + last-block-per-batch select ----------
__global__ __launch_bounds__(256) void bucket_select_k(const float* __restrict__ scores,
                                                       uint32_t* __restrict__ ws) {
    __shared__ union {
        struct { uint32_t wh[4][256]; uint32_t wcur[4][256]; uint32_t sorted[SLICE_PTS]; } bk;
        struct { uint32_t list[LIST_CAP]; } sel;
    } U;
    __shared__ uint32_t htmp[256], excl[256];
    __shared__ uint32_t lens[HSLICES], starts[HSLICES], outoff[HSLICES];
    __shared__ uint32_t sBin, sKrem, sE, sTot, sCnt, sIstar, sRun, sLast;

    const int b = blockIdx.y, sl = blockIdx.x;
    const int tid = threadIdx.x, w = tid >> 6, lane = tid & 63;

    // ---- bucket phase ----
#pragma unroll
    for (int j = 0; j < 4; ++j) U.bk.wh[j][tid] = 0;
    __syncthreads();
    const int p0 = sl * SLICE_PTS + tid * 4;
    uint32_t u[4];
    const bool valid = p0 < NPTS;
    if (valid) {
        const float4 v = *reinterpret_cast<const float4*>(scores + (size_t)b * NPTS + p0);
        u[0] = fmap(v.x); u[1] = fmap(v.y); u[2] = fmap(v.z); u[3] = fmap(v.w);
#pragma unroll
        for (int j = 0; j < 4; ++j) atomicAdd(&U.bk.wh[w][u[j] >> 24], 1u);
    }
    __syncthreads();
    const uint32_t c0 = U.bk.wh[0][tid], c1 = U.bk.wh[1][tid];
    const uint32_t c2 = U.bk.wh[2][tid], c3 = U.bk.wh[3][tid];
    const uint32_t ht = c0 + c1 + c2 + c3;
    htmp[tid] = ht;
    __syncthreads();
    if (tid < 64) {  // wave-0 exclusive prefix over 256 bins, 4/lane
        const uint32_t v0 = htmp[4*tid], v1 = htmp[4*tid+1], v2 = htmp[4*tid+2], v3 = htmp[4*tid+3];
        const uint32_t lt = v0 + v1 + v2 + v3;
        uint32_t x = lt;
#pragma unroll
        for (int off = 1; off < 64; off <<= 1) {
            const uint32_t y = __shfl_up(x, off);
            if (lane >= off) x += y;
        }
        const uint32_t ex = x - lt;
        excl[4*tid] = ex; excl[4*tid+1] = ex + v0;
        excl[4*tid+2] = ex + v0 + v1; excl[4*tid+3] = ex + v0 + v1 + v2;
    }
    __syncthreads();
    const uint32_t e = excl[tid];
    U.bk.wcur[0][tid] = e;
    U.bk.wcur[1][tid] = e + c0;
    U.bk.wcur[2][tid] = e + c0 + c1;
    U.bk.wcur[3][tid] = e + c0 + c1 + c2;
    const size_t sb = ((size_t)(b * HSLICES + sl)) * 256;
    ws[HISTG_OFF + sb + tid] = ht;
    ws[PREFG_OFF + sb + tid] = e;
    __syncthreads();
    if (valid) {
#pragma unroll
        for (int j = 0; j < 4; ++j) {
            const uint32_t pos = atomicAdd(&U.bk.wcur[w][u[j] >> 24], 1u);
            U.bk.sorted[pos] = u[j];
        }
    }
    __syncthreads();
    const int n = min(SLICE_PTS, NPTS - sl * SLICE_PTS);
    uint32_t* gv = ws + VALS_OFF + ((size_t)(b * HSLICES + sl)) * SLICE_PTS;
    if (n == SLICE_PTS) {
        reinterpret_cast<uint4*>(gv)[tid] = reinterpret_cast<const uint4*>(U.bk.sorted)[tid];
    } else {
        for (int i = tid; i < n; i += 256) gv[i] = U.bk.sorted[i];
    }

    // ---- last-block detection (release/acquire, device scope) ----
    __threadfence();   // release this block's global writes
    if (tid == 0) sLast = (atomicAdd(&ws[CTR_OFF + b], 1u) == HSLICES - 1) ? 1u : 0u;
    __syncthreads();
    if (!sLast) return;
    __threadfence();   // acquire other blocks' writes

    // ---- select phase (one block per batch, 256 threads) ----
    if (tid == 0) sIstar = NPTS;
    // Phase A: reduce per-slice hists -> batch hist (htmp)
    {
        const uint32_t* hb = ws + HISTG_OFF + (size_t)b * HSLICES * 256;
        uint32_t acc = 0;
#pragma unroll 7
        for (int s = 0; s < HSLICES; ++s) acc += hb[(size_t)s * 256 + tid];
        htmp[tid] = acc;
    }

    // wave_select #0: bin containing the KTOP-th largest (suffix-sum pick)
    uint32_t prefix, beta;
    {
        __syncthreads();
        if (tid < 64) {
            const uint32_t v0 = htmp[4*tid], v1 = htmp[4*tid+1], v2 = htmp[4*tid+2], v3 = htmp[4*tid+3];
            const uint32_t lt = v0 + v1 + v2 + v3;
            uint32_t x = lt;
#pragma unroll
            for (int off = 1; off < 64; off <<= 1) {
                const uint32_t y = __shfl_up(x, off);
                if (lane >= off) x += y;
            }
            const uint32_t ex = x - lt;
            excl[4*tid] = ex; excl[4*tid+1] = ex + v0;
            excl[4*tid+2] = ex + v0 + v1; excl[4*tid+3] = ex + v0 + v1 + v2;
            if (tid == 63) sTot = x;
        }
        __syncthreads();
        {
            const uint32_t total = sTot, lim = total - KTOP;
            const uint32_t pe = excl[tid];
            const uint32_t pe1 = (tid == 255) ? total : excl[tid + 1];
            if (pe <= lim && pe1 > lim) {
                sBin = (uint32_t)tid;
                sKrem = KTOP - (total - pe1);
            }
        }
        __syncthreads();
        beta = sBin;
        prefix = beta << 24;
    }

    // Phase B: per-slice segment table for bin beta + exclusive scan of lens
    if (tid < HSLICES) {
        const size_t sb2 = ((size_t)(b * HSLICES + tid)) * 256;
        lens[tid] = ws[HISTG_OFF + sb2 + beta];
        starts[tid] = ws[PREFG_OFF + sb2 + beta];
    }
    __syncthreads();
    if (tid < 64) {  // exclusive scan of 98 lens, 2/lane
        uint32_t a = 0, b2 = 0;
        if (tid < 49) { a = lens[2*tid]; if (2*tid + 1 < HSLICES) b2 = lens[2*tid+1]; }
        const uint32_t lt = a + b2;
        uint32_t x = lt;
#pragma unroll
        for (int off = 1; off < 64; off <<= 1) {
            const uint32_t y = __shfl_up(x, off);
            if (lane >= off) x += y;
        }
        const uint32_t ex = x - lt;
        if (tid < 49) { outoff[2*tid] = ex; if (2*tid + 1 < HSLICES) outoff[2*tid+1] = ex + a; }
        if (tid == 63) sCnt = x;
    }
    __syncthreads();
    uint32_t cnt = sCnt;
    if (cnt > LIST_CAP) cnt = LIST_CAP;

    // gather candidates into LDS list (flattened, binary-search slice lookup)
    for (uint32_t i = tid; i < cnt; i += 256) {
        int lo = 0, hi = HSLICES - 1;
        while (lo < hi) { const int mid = (lo + hi + 1) >> 1; if (outoff[mid] <= i) lo = mid; else hi = mid - 1; }
        const uint32_t j = i - outoff[lo];
        U.sel.list[i] = ws[VALS_OFF + ((size_t)(b * HSLICES + lo)) * SLICE_PTS + starts[lo] + j];
    }

    // Phase C: 3 radix passes over the candidate list
#pragma unroll 1
    for (int shift = 16; shift >= 0; shift -= 8) {
        __syncthreads();
        htmp[tid] = 0;
        __syncthreads();
        const uint32_t hi8 = prefix >> (shift + 8);
        for (uint32_t i = tid; i < cnt; i += 256) {
            const uint32_t uu = U.sel.list[i];
            if ((uu >> (shift + 8)) == hi8)
                atomicAdd(&htmp[(uu >> shift) & 255u], 1u);
        }
        __syncthreads();
        if (tid < 64) {
            const uint32_t v0 = htmp[4*tid], v1 = htmp[4*tid+1], v2 = htmp[4*tid+2], v3 = htmp[4*tid+3];
            const uint32_t lt = v0 + v1 + v2 + v3;
            uint32_t x = lt;
#pragma unroll
            for (int off = 1; off < 64; off <<= 1) {
                const uint32_t y = __shfl_up(x, off);
                if (lane >= off) x += y;
            }
            const uint32_t ex = x - lt;
            excl[4*tid] = ex; excl[4*tid+1] = ex + v0;
            excl[4*tid+2] = ex + v0 + v1; excl[4*tid+3] = ex + v0 + v1 + v2;
            if (tid == 63) sTot = x;
        }
        __syncthreads();
        {
            const uint32_t target = sKrem;
            const uint32_t total = sTot, lim = total - target;
            const uint32_t pe = excl[tid];
            const uint32_t pe1 = (tid == 255) ? total : excl[tid + 1];
            if (pe <= lim && pe1 > lim) {
                sBin = (uint32_t)tid;
                sKrem = target - (total - pe1);
                if (shift == 0) sE = pe1 - pe;
            }
        }
        __syncthreads();
        prefix |= sBin << shift;
    }

    const uint32_t R = sKrem, E = sE;
    const uint32_t tbits = (prefix & 0x80000000u) ? (prefix & 0x7fffffffu) : ~prefix;

    if (E != R) {
        // rare: find global index of the 0-based rank-R element equal to T
        __shared__ uint32_t wcnt2[4];
        const float T = __uint_as_float(tbits);
        if (tid == 0) sRun = 0;
        __syncthreads();
        const float* sc = scores + (size_t)b * NPTS;
        const int wid = tid >> 6;
        for (int base = 0; base < NPTS; base += 256) {
            const uint32_t r0 = sRun;
            if (r0 > R) break;
            const int i = base + tid;
            const bool eq = (i < NPTS) && (sc[i] == T);
            const unsigned long long mask = __ballot(eq);
            if (lane == 0) wcnt2[wid] = (uint32_t)__popcll(mask);
            __syncthreads();
            uint32_t before = 0, total = 0;
            for (int ww = 0; ww < 4; ++ww) {
                const uint32_t c = wcnt2[ww];
                if (ww < wid) before += c;
                total += c;
            }
            if (eq) {
                const uint32_t rank = r0 + before +
                    (uint32_t)__popcll(mask & ((1ull << lane) - 1ull));
                if (rank == R) sIstar = (uint32_t)i;
            }
            __syncthreads();
            if (tid == 0) sRun = r0 + total;
            __syncthreads();
        }
        __syncthreads();
    }
    if (tid == 0) {
        uint32_t* st = ws + STATE_OFF + b * 2;
        st[0] = tbits;   // threshold T as float bits
        st[1] = sIstar;  // ties: s==T taken iff idx < Istar
    }
}

// ---------- exact (numpy-bit-identical) gt check for one point ----------
__device__ __noinline__ bool exact_gt(float px, float py, float pz,
                                      const float* __restrict__ C) {
    bool hit = false;
#pragma unroll 1
    for (int k = 0; k < NBOX; ++k) {
        float dx = px - C[3 * k + 0];
        float dy = py - C[3 * k + 1];
        float dz = pz - C[3 * k + 2];
        float d2 = __fadd_rn(__fadd_rn(__fmul_rn(dx, dx), __fmul_rn(dy, dy)),
                             __fmul_rn(dz, dz));
        if (__fsqrt_rn(d2) < THRF) hit = true;
    }
    return hit;
}

// ---------- K2: gt mask + prune mask + losses ----------
__global__ __launch_bounds__(256) void main_k(const float* __restrict__ scores,
                                              const float* __restrict__ points,
                                              const float* __restrict__ ctrs,
                                              const uint32_t* __restrict__ ws,
                                              float* __restrict__ out) {
    const int b = blockIdx.y;
    const uint32_t* st = ws + STATE_OFF + b * 2;
    const float T = __uint_as_float(st[0]);
    const uint32_t Istar = st[1];

    const int p0 = blockIdx.x * 1024 + threadIdx.x * 4;
    if (p0 >= NPTS) return;

    const float* P = points + ((size_t)b * NPTS + p0) * 3;
    const float4 a = *reinterpret_cast<const float4*>(P);
    const float4 c4 = *reinterpret_cast<const float4*>(P + 4);
    const float4 e = *reinterpret_cast<const float4*>(P + 8);
    const float px[4] = {a.x, a.w, c4.z, e.y};
    const float py[4] = {a.y, c4.x, c4.w, e.z};
    const float pz[4] = {a.z, c4.y, e.x, e.w};
    // d^2 = p.p + (c.c - 2 p.c); min commutes with +p.p (per-point constant)
    float m2[4] = {1e30f, 1e30f, 1e30f, 1e30f};

    const float* C = ctrs + b * NBOX * 3;
#pragma unroll 16
    for (int k = 0; k < NBOX; ++k) {
        const float cx = C[3 * k + 0];
        const float cy = C[3 * k + 1];
        const float cz = C[3 * k + 2];
        const float cc = fmaf(cx, cx, fmaf(cy, cy, cz * cz));
        const float m2x = -2.0f * cx, m2y = -2.0f * cy, m2z = -2.0f * cz;
#pragma unroll
        for (int j = 0; j < 4; ++j) {
            const float t = fmaf(m2x, px[j], fmaf(m2y, py[j], fmaf(m2z, pz[j], cc)));
            m2[j] = fminf(m2[j], t);
        }
    }

    const float4 sv = *reinterpret_cast<const float4*>(scores + (size_t)b * NPTS + p0);
    const float s[4] = {sv.x, sv.y, sv.z, sv.w};
    float pr[4], ls[4];
#pragma unroll
    for (int j = 0; j < 4; ++j) {
        const float pp = fmaf(px[j], px[j], fmaf(py[j], py[j], pz[j] * pz[j]));
        const float m = pp + m2[j];
        bool gt;
        if (m < C_LO) gt = true;
        else if (m >= C_HI) gt = false;
        else gt = exact_gt(px[j], py[j], pz[j], C);  // rare boundary band
        const bool sm = (s[j] > T) || (s[j] == T && (uint32_t)(p0 + j) < Istar);
        pr[j] = (gt || sm) ? 1.0f : 0.0f;
        const float x = gt ? -s[j] : s[j];
        // fast softplus: tolerance is bf16-level (9.4e-2); hw exp/log err ~1e-6
        ls[j] = fmaxf(x, 0.0f) + __logf(1.0f + __expf(-fabsf(s[j])));
    }
    float* o0 = out + (size_t)b * NPTS + p0;
    float* o1 = out + (size_t)BB * NPTS + (size_t)b * NPTS + p0;
    *reinterpret_cast<float4*>(o0) = make_float4(pr[0], pr[1], pr[2], pr[3]);
    *reinterpret_cast<float4*>(o1) = make_float4(ls[0], ls[1], ls[2], ls[3]);
}

extern "C" void kernel_launch(void* const* d_in, const int* in_sizes, int n_in,
                              void* d_out, int out_size, void* d_ws, size_t ws_size,
                              hipStream_t stream) {
    const float* scores = (const float*)d_in[0];
    const float* points = (const float*)d_in[1];
    const float* ctrs   = (const float*)d_in[2];
    float* out = (float*)d_out;
    uint32_t* ws = (uint32_t*)d_ws;

    // zero only the BB done-counters (64 B)
    hipMemsetAsync((char*)d_ws + (size_t)CTR_OFF * 4, 0, BB * 4, stream);

    const dim3 gridP(HSLICES, BB);  // 98 x 16
    bucket_select_k<<<gridP, 256, 0, stream>>>(scores, ws);
    main_k<<<gridP, 256, 0, stream>>>(scores, points, ctrs, ws, out);
}

// Round 7
// 140.860 us; speedup vs baseline: 1.3676x; 1.3676x over previous
//
#include <hip/hip_runtime.h>
#include <hip/hip_bf16.h>
#include <stdint.h>

// Problem constants
#define BB 16
#define NPTS 100000
#define NBOX 64
#define KTOP 2048
#define THRF 0.2f            // (float)(8*0.01*2.5)
// band around 0.2^2 for exact-path fallback; fast path error bound ~5e-6
#define C_LO 0.039984f
#define C_HI 0.040016f

#define HSLICES 98
#define SLICE_PTS 1024
#define LIST_CAP 4096        // candidates expected ~2275 +/- 47 (>=25 sigma margin)

// Workspace layout (uint32 words). HIST+CTR zeroed by one 16.4 KB memset.
// NOTE: no plain global stores in K1 before the handshake — hist is built with
// device-scope atomics only, so the release side needs NO L2 writeback (the
// round-6 regression was 1568 blocks each flushing ~9 MB of dirty L2).
#define HIST_OFF  0                  // BB*256 global per-batch histogram (atomics)
#define CTR_OFF   (BB * 256)         // BB done-counters
#define STATE_OFF (BB * 256 + BB)    // BB*2 {T_bits, Istar} (plain stores, inter-kernel)
#define MEMSET_BYTES ((BB * 256 + BB) * 4)

__device__ __forceinline__ uint32_t fmap(float f) {
    uint32_t b = __float_as_uint(f);
    return (b & 0x80000000u) ? ~b : (b | 0x80000000u);
}

// ---------- K1: per-slice hist -> global atomic hist; last block per batch selects ----------
__global__ __launch_bounds__(256) void hist_select_k(const float* __restrict__ scores,
                                                     uint32_t* __restrict__ ws) {
    __shared__ uint32_t wh[4][256];   // per-wave sub-hists / reused as radix hist
    __shared__ uint32_t excl[256];    // prefix-scan scratch
    __shared__ uint32_t list[LIST_CAP];
    __shared__ uint32_t sBin, sKrem, sE, sTot, sIstar, sRun, sLast, lcnt;

    const int b = blockIdx.y, sl = blockIdx.x;
    const int tid = threadIdx.x, w = tid >> 6, lane = tid & 63;

    // ---- hist phase (all 1568 blocks) ----
#pragma unroll
    for (int j = 0; j < 4; ++j) wh[j][tid] = 0;
    __syncthreads();
    const int p0 = sl * SLICE_PTS + tid * 4;
    if (p0 < NPTS) {
        const float4 v = *reinterpret_cast<const float4*>(scores + (size_t)b * NPTS + p0);
        atomicAdd(&wh[w][fmap(v.x) >> 24], 1u);
        atomicAdd(&wh[w][fmap(v.y) >> 24], 1u);
        atomicAdd(&wh[w][fmap(v.z) >> 24], 1u);
        atomicAdd(&wh[w][fmap(v.w) >> 24], 1u);
    }
    __syncthreads();
    const uint32_t ht = wh[0][tid] + wh[1][tid] + wh[2][tid] + wh[3][tid];
    if (ht) atomicAdd(&ws[HIST_OFF + b * 256 + tid], ht);  // device-scope, coherent
    __syncthreads();  // barrier drain (vmcnt 0): all this block's atomics complete

    // ---- last-block handshake: atomics only, no dirty-L2 release needed ----
    if (tid == 0) sLast = (atomicAdd(&ws[CTR_OFF + b], 1u) == HSLICES - 1) ? 1u : 0u;
    __syncthreads();
    if (!sLast) return;
    __threadfence();  // acquire: invalidate potentially-stale cached lines (cheap: nothing dirty)

    // ---- select phase (one 256-thread block per batch) ----
    if (tid == 0) { sIstar = NPTS; lcnt = 0; }
    // coherent read of the batch histogram
    {
        uint32_t hv = __hip_atomic_load(&ws[HIST_OFF + b * 256 + tid],
                                        __ATOMIC_RELAXED, __HIP_MEMORY_SCOPE_AGENT);
        wh[0][tid] = hv;
    }
    __syncthreads();
    // suffix-select MSB bin: wave-0 exclusive prefix over 256 bins, 4/lane
    if (tid < 64) {
        const uint32_t v0 = wh[0][4*tid], v1 = wh[0][4*tid+1], v2 = wh[0][4*tid+2], v3 = wh[0][4*tid+3];
        const uint32_t lt = v0 + v1 + v2 + v3;
        uint32_t x = lt;
#pragma unroll
        for (int off = 1; off < 64; off <<= 1) {
            const uint32_t y = __shfl_up(x, off);
            if (lane >= off) x += y;
        }
        const uint32_t ex = x - lt;
        excl[4*tid] = ex; excl[4*tid+1] = ex + v0;
        excl[4*tid+2] = ex + v0 + v1; excl[4*tid+3] = ex + v0 + v1 + v2;
        if (tid == 63) sTot = x;
    }
    __syncthreads();
    {
        const uint32_t total = sTot, lim = total - KTOP;
        const uint32_t pe = excl[tid];
        const uint32_t pe1 = (tid == 255) ? total : excl[tid + 1];
        if (pe <= lim && pe1 > lim) {  // unique interval containing lim
            sBin = (uint32_t)tid;
            sKrem = KTOP - (total - pe1);
        }
    }
    __syncthreads();
    uint32_t prefix = sBin << 24;
    const uint32_t beta = sBin;

    // compact candidates (MSB byte == beta) from clean input into LDS, ballot-aggregated
    {
        const unsigned long long lmask = (1ull << lane) - 1ull;
        const float* sc = scores + (size_t)b * NPTS;
        for (int i4 = tid; i4 < NPTS / 4; i4 += 256) {
            const float4 v = *reinterpret_cast<const float4*>(sc + i4 * 4);
            uint32_t u[4] = {fmap(v.x), fmap(v.y), fmap(v.z), fmap(v.w)};
#pragma unroll
            for (int j = 0; j < 4; ++j) {
                const bool m = (u[j] >> 24) == beta;
                const unsigned long long mask = __ballot(m);
                if (mask) {
                    uint32_t base = 0;
                    if (lane == 0) base = atomicAdd(&lcnt, (uint32_t)__popcll(mask));
                    base = __shfl(base, 0);
                    if (m) {
                        const uint32_t pos = base + (uint32_t)__popcll(mask & lmask);
                        if (pos < LIST_CAP) list[pos] = u[j];
                    }
                }
            }
        }
    }
    __syncthreads();
    uint32_t cnt = lcnt;
    if (cnt > LIST_CAP) cnt = LIST_CAP;

    // 3 radix passes over the candidate list
#pragma unroll 1
    for (int shift = 16; shift >= 0; shift -= 8) {
        __syncthreads();
        wh[0][tid] = 0;
        __syncthreads();
        const uint32_t hi8 = prefix >> (shift + 8);
        for (uint32_t i = tid; i < cnt; i += 256) {
            const uint32_t uu = list[i];
            if ((uu >> (shift + 8)) == hi8)
                atomicAdd(&wh[0][(uu >> shift) & 255u], 1u);
        }
        __syncthreads();
        if (tid < 64) {
            const uint32_t v0 = wh[0][4*tid], v1 = wh[0][4*tid+1], v2 = wh[0][4*tid+2], v3 = wh[0][4*tid+3];
            const uint32_t lt = v0 + v1 + v2 + v3;
            uint32_t x = lt;
#pragma unroll
            for (int off = 1; off < 64; off <<= 1) {
                const uint32_t y = __shfl_up(x, off);
                if (lane >= off) x += y;
            }
            const uint32_t ex = x - lt;
            excl[4*tid] = ex; excl[4*tid+1] = ex + v0;
            excl[4*tid+2] = ex + v0 + v1; excl[4*tid+3] = ex + v0 + v1 + v2;
            if (tid == 63) sTot = x;
        }
        __syncthreads();
        {
            const uint32_t target = sKrem;
            const uint32_t total = sTot, lim = total - target;
            const uint32_t pe = excl[tid];
            const uint32_t pe1 = (tid == 255) ? total : excl[tid + 1];
            if (pe <= lim && pe1 > lim) {
                sBin = (uint32_t)tid;
                sKrem = target - (total - pe1);
                if (shift == 0) sE = pe1 - pe;
            }
        }
        __syncthreads();
        prefix |= sBin << shift;
    }

    const uint32_t R = sKrem, E = sE;
    const uint32_t tbits = (prefix & 0x80000000u) ? (prefix & 0x7fffffffu) : ~prefix;

    if (E != R) {
        // rare: find global index of the 0-based rank-R element equal to T
        __shared__ uint32_t wcnt2[4];
        const float T = __uint_as_float(tbits);
        if (tid == 0) sRun = 0;
        __syncthreads();
        const float* sc = scores + (size_t)b * NPTS;
        const int wid = tid >> 6;
        for (int base = 0; base < NPTS; base += 256) {
            const uint32_t r0 = sRun;
            if (r0 > R) break;
            const int i = base + tid;
            const bool eq = (i < NPTS) && (sc[i] == T);
            const unsigned long long mask = __ballot(eq);
            if (lane == 0) wcnt2[wid] = (uint32_t)__popcll(mask);
            __syncthreads();
            uint32_t before = 0, total = 0;
            for (int ww = 0; ww < 4; ++ww) {
                const uint32_t c = wcnt2[ww];
                if (ww < wid) before += c;
                total += c;
            }
            if (eq) {
                const uint32_t rank = r0 + before +
                    (uint32_t)__popcll(mask & ((1ull << lane) - 1ull));
                if (rank == R) sIstar = (uint32_t)i;
            }
            __syncthreads();
            if (tid == 0) sRun = r0 + total;
            __syncthreads();
        }
        __syncthreads();
    }
    if (tid == 0) {
        uint32_t* st = ws + STATE_OFF + b * 2;
        st[0] = tbits;   // threshold T as float bits
        st[1] = sIstar;  // ties: s==T taken iff idx < Istar
    }
}

// ---------- exact (numpy-bit-identical) gt check for one point ----------
__device__ __noinline__ bool exact_gt(float px, float py, float pz,
                                      const float* __restrict__ C) {
    bool hit = false;
#pragma unroll 1
    for (int k = 0; k < NBOX; ++k) {
        float dx = px - C[3 * k + 0];
        float dy = py - C[3 * k + 1];
        float dz = pz - C[3 * k + 2];
        float d2 = __fadd_rn(__fadd_rn(__fmul_rn(dx, dx), __fmul_rn(dy, dy)),
                             __fmul_rn(dz, dz));
        if (__fsqrt_rn(d2) < THRF) hit = true;
    }
    return hit;
}

// ---------- K2: gt mask + prune mask + losses ----------
__global__ __launch_bounds__(256) void main_k(const float* __restrict__ scores,
                                              const float* __restrict__ points,
                                              const float* __restrict__ ctrs,
                                              const uint32_t* __restrict__ ws,
                                              float* __restrict__ out) {
    const int b = blockIdx.y;
    const uint32_t* st = ws + STATE_OFF + b * 2;
    const float T = __uint_as_float(st[0]);
    const uint32_t Istar = st[1];

    const int p0 = blockIdx.x * 1024 + threadIdx.x * 4;
    if (p0 >= NPTS) return;

    const float* P = points + ((size_t)b * NPTS + p0) * 3;
    const float4 a = *reinterpret_cast<const float4*>(P);
    const float4 c4 = *reinterpret_cast<const float4*>(P + 4);
    const float4 e = *reinterpret_cast<const float4*>(P + 8);
    const float px[4] = {a.x, a.w, c4.z, e.y};
    const float py[4] = {a.y, c4.x, c4.w, e.z};
    const float pz[4] = {a.z, c4.y, e.x, e.w};
    // d^2 = p.p + (c.c - 2 p.c); min commutes with +p.p (per-point constant)
    float m2[4] = {1e30f, 1e30f, 1e30f, 1e30f};

    const float* C = ctrs + b * NBOX * 3;
#pragma unroll 16
    for (int k = 0; k < NBOX; ++k) {
        const float cx = C[3 * k + 0];
        const float cy = C[3 * k + 1];
        const float cz = C[3 * k + 2];
        const float cc = fmaf(cx, cx, fmaf(cy, cy, cz * cz));
        const float m2x = -2.0f * cx, m2y = -2.0f * cy, m2z = -2.0f * cz;
#pragma unroll
        for (int j = 0; j < 4; ++j) {
            const float t = fmaf(m2x, px[j], fmaf(m2y, py[j], fmaf(m2z, pz[j], cc)));
            m2[j] = fminf(m2[j], t);
        }
    }

    const float4 sv = *reinterpret_cast<const float4*>(scores + (size_t)b * NPTS + p0);
    const float s[4] = {sv.x, sv.y, sv.z, sv.w};
    float pr[4], ls[4];
#pragma unroll
    for (int j = 0; j < 4; ++j) {
        const float pp = fmaf(px[j], px[j], fmaf(py[j], py[j], pz[j] * pz[j]));
        const float m = pp + m2[j];
        bool gt;
        if (m < C_LO) gt = true;
        else if (m >= C_HI) gt = false;
        else gt = exact_gt(px[j], py[j], pz[j], C);  // rare boundary band
        const bool sm = (s[j] > T) || (s[j] == T && (uint32_t)(p0 + j) < Istar);
        pr[j] = (gt || sm) ? 1.0f : 0.0f;
        const float x = gt ? -s[j] : s[j];
        // fast softplus: tolerance is bf16-level (9.4e-2); hw exp/log err ~1e-6
        ls[j] = fmaxf(x, 0.0f) + __logf(1.0f + __expf(-fabsf(s[j])));
    }
    float* o0 = out + (size_t)b * NPTS + p0;
    float* o1 = out + (size_t)BB * NPTS + (size_t)b * NPTS + p0;
    *reinterpret_cast<float4*>(o0) = make_float4(pr[0], pr[1], pr[2], pr[3]);
    *reinterpret_cast<float4*>(o1) = make_float4(ls[0], ls[1], ls[2], ls[3]);
}

extern "C" void kernel_launch(void* const* d_in, const int* in_sizes, int n_in,
                              void* d_out, int out_size, void* d_ws, size_t ws_size,
                              hipStream_t stream) {
    const float* scores = (const float*)d_in[0];
    const float* points = (const float*)d_in[1];
    const float* ctrs   = (const float*)d_in[2];
    float* out = (float*)d_out;
    uint32_t* ws = (uint32_t*)d_ws;

    // zero the global histogram + done-counters (16.4 KB)
    hipMemsetAsync(d_ws, 0, MEMSET_BYTES, stream);

    const dim3 gridP(HSLICES, BB);  // 98 x 16
    hist_select_k<<<gridP, 256, 0, stream>>>(scores, ws);
    main_k<<<gridP, 256, 0, stream>>>(scores, points, ctrs, ws, out);
}

// Round 8
// 73.295 us; speedup vs baseline: 2.6283x; 1.9218x over previous
//
#include <hip/hip_runtime.h>
#include <hip/hip_bf16.h>
#include <stdint.h>

// Problem constants
#define BB 16
#define NPTS 100000
#define NBOX 64
#define KTOP 2048
#define THRF 0.2f            // (float)(8*0.01*2.5)
// band around 0.2^2 for exact-path fallback; fast path error bound ~5e-6
#define C_LO 0.039984f
#define C_HI 0.040016f

#define LIST_CAP 4096        // candidates expected ~2275 +/- 47 (>=38 sigma margin)
#define NF4 (NPTS / 4)       // 25000 float4s per batch

// Workspace: only BB*2 words {T_bits, Istar}; written by K1, read by K2
// (kernel boundary = coherence point; no memset, no fences, no global atomics)
#define STATE_OFF 0

__device__ __forceinline__ uint32_t fmap(float f) {
    uint32_t b = __float_as_uint(f);
    return (b & 0x80000000u) ? ~b : (b | 0x80000000u);
}

// ---------- K1: one block per batch does the whole top-K selection ----------
__global__ __launch_bounds__(1024) void select_k(const float* __restrict__ scores,
                                                 uint32_t* __restrict__ ws) {
    const int b = blockIdx.x, tid = threadIdx.x, w = tid >> 6, lane = tid & 63;
    __shared__ uint32_t wh[16][256];   // per-wave MSB hists (reduce is bank-conflict-free)
    __shared__ uint32_t hist[256], excl[256];
    __shared__ uint32_t list[LIST_CAP];
    __shared__ uint32_t sBin, sKrem, sE, sTot, sIstar, sRun;

    reinterpret_cast<uint4*>(&wh[0][0])[tid] = make_uint4(0, 0, 0, 0);
    if (tid == 0) sIstar = NPTS;
    __syncthreads();

    const float4* sc4 = reinterpret_cast<const float4*>(scores + (size_t)b * NPTS);

    // ---- pass 1: per-wave 256-bin MSB histogram (2-wide unrolled loads) ----
    {
        uint32_t* mh = wh[w];
        int i4 = tid;
#pragma unroll 1
        for (int it = 0; it < 12; ++it, i4 += 2048) {
            const float4 v0 = sc4[i4];
            const float4 v1 = sc4[i4 + 1024];
            atomicAdd(&mh[fmap(v0.x) >> 24], 1u);
            atomicAdd(&mh[fmap(v0.y) >> 24], 1u);
            atomicAdd(&mh[fmap(v0.z) >> 24], 1u);
            atomicAdd(&mh[fmap(v0.w) >> 24], 1u);
            atomicAdd(&mh[fmap(v1.x) >> 24], 1u);
            atomicAdd(&mh[fmap(v1.y) >> 24], 1u);
            atomicAdd(&mh[fmap(v1.z) >> 24], 1u);
            atomicAdd(&mh[fmap(v1.w) >> 24], 1u);
        }
        if (i4 < NF4) {  // tail: 424 float4s
            const float4 v = sc4[i4];
            atomicAdd(&mh[fmap(v.x) >> 24], 1u);
            atomicAdd(&mh[fmap(v.y) >> 24], 1u);
            atomicAdd(&mh[fmap(v.z) >> 24], 1u);
            atomicAdd(&mh[fmap(v.w) >> 24], 1u);
        }
    }
    __syncthreads();
    if (tid < 256) {  // reduce 16 sub-hists (per step: 64 lanes / 32 banks = free)
        uint32_t acc = 0;
#pragma unroll
        for (int j = 0; j < 16; ++j) acc += wh[j][tid];
        hist[tid] = acc;
    }
    __syncthreads();

    // ---- MSB bin pick: wave-0 exclusive prefix + unique-interval select ----
    if (tid < 64) {
        const uint32_t v0 = hist[4*tid], v1 = hist[4*tid+1], v2 = hist[4*tid+2], v3 = hist[4*tid+3];
        const uint32_t lt = v0 + v1 + v2 + v3;
        uint32_t x = lt;
#pragma unroll
        for (int off = 1; off < 64; off <<= 1) {
            const uint32_t y = __shfl_up(x, off);
            if (lane >= off) x += y;
        }
        const uint32_t ex = x - lt;
        excl[4*tid] = ex; excl[4*tid+1] = ex + v0;
        excl[4*tid+2] = ex + v0 + v1; excl[4*tid+3] = ex + v0 + v1 + v2;
        if (tid == 63) sTot = x;
    }
    __syncthreads();
    if (tid < 256) {
        const uint32_t total = sTot, lim = total - KTOP;
        const uint32_t pe = excl[tid];
        const uint32_t pe1 = (tid == 255) ? total : excl[tid + 1];
        if (pe <= lim && pe1 > lim) {  // unique interval containing lim
            sBin = (uint32_t)tid;
            sKrem = KTOP - (total - pe1);
        }
    }
    __syncthreads();
    const uint32_t beta = sBin;
    uint32_t prefix = beta << 24;
    uint32_t cnt = hist[beta];
    if (cnt > LIST_CAP) cnt = LIST_CAP;

    // ---- pass 2: compact bin-beta candidates into LDS, ZERO atomics ----
    // wave w's segment base = sum of other waves' beta-counts below it (from pass-1 hists);
    // within-wave positions via ballot popcounts; cursor update is wave-uniform.
    {
        uint32_t wbase = 0;
#pragma unroll
        for (int j = 0; j < 16; ++j) wbase += (j < w) ? wh[j][beta] : 0u;
        const unsigned long long lmask = (1ull << lane) - 1ull;
        uint32_t cursor = wbase;
        int i4 = tid;
#pragma unroll 1
        for (int it = 0; it < 12; ++it, i4 += 2048) {
            const float4 v0 = sc4[i4];
            const float4 v1 = sc4[i4 + 1024];
            uint32_t u[8] = {fmap(v0.x), fmap(v0.y), fmap(v0.z), fmap(v0.w),
                             fmap(v1.x), fmap(v1.y), fmap(v1.z), fmap(v1.w)};
#pragma unroll
            for (int j = 0; j < 8; ++j) {
                const bool m = (u[j] >> 24) == beta;
                const unsigned long long mask = __ballot(m);
                if (m) {
                    const uint32_t pos = cursor + (uint32_t)__popcll(mask & lmask);
                    if (pos < LIST_CAP) list[pos] = u[j];
                }
                cursor += (uint32_t)__popcll(mask);
            }
        }
        {   // tail: OOB lanes feed u=0 (bin 0 != beta) to keep ballot/cursor uniform
            const bool ib = i4 < NF4;
            float4 v = make_float4(0.f, 0.f, 0.f, 0.f);
            if (ib) v = sc4[i4];
            uint32_t u[4] = {ib ? fmap(v.x) : 0u, ib ? fmap(v.y) : 0u,
                             ib ? fmap(v.z) : 0u, ib ? fmap(v.w) : 0u};
#pragma unroll
            for (int j = 0; j < 4; ++j) {
                const bool m = (u[j] >> 24) == beta;
                const unsigned long long mask = __ballot(m);
                if (m) {
                    const uint32_t pos = cursor + (uint32_t)__popcll(mask & lmask);
                    if (pos < LIST_CAP) list[pos] = u[j];
                }
                cursor += (uint32_t)__popcll(mask);
            }
        }
    }

    // ---- 3 radix passes over the candidate list ----
#pragma unroll 1
    for (int shift = 16; shift >= 0; shift -= 8) {
        __syncthreads();
        if (tid < 256) hist[tid] = 0;
        __syncthreads();
        const uint32_t hi8 = prefix >> (shift + 8);
        for (uint32_t i = tid; i < cnt; i += 1024) {
            const uint32_t uu = list[i];
            if ((uu >> (shift + 8)) == hi8)
                atomicAdd(&hist[(uu >> shift) & 255u], 1u);
        }
        __syncthreads();
        if (tid < 64) {
            const uint32_t v0 = hist[4*tid], v1 = hist[4*tid+1], v2 = hist[4*tid+2], v3 = hist[4*tid+3];
            const uint32_t lt = v0 + v1 + v2 + v3;
            uint32_t x = lt;
#pragma unroll
            for (int off = 1; off < 64; off <<= 1) {
                const uint32_t y = __shfl_up(x, off);
                if (lane >= off) x += y;
            }
            const uint32_t ex = x - lt;
            excl[4*tid] = ex; excl[4*tid+1] = ex + v0;
            excl[4*tid+2] = ex + v0 + v1; excl[4*tid+3] = ex + v0 + v1 + v2;
            if (tid == 63) sTot = x;
        }
        __syncthreads();
        if (tid < 256) {
            const uint32_t target = sKrem;
            const uint32_t total = sTot, lim = total - target;
            const uint32_t pe = excl[tid];
            const uint32_t pe1 = (tid == 255) ? total : excl[tid + 1];
            if (pe <= lim && pe1 > lim) {
                sBin = (uint32_t)tid;
                sKrem = target - (total - pe1);
                if (shift == 0) sE = pe1 - pe;
            }
        }
        __syncthreads();
        prefix |= sBin << shift;
    }

    const uint32_t R = sKrem, E = sE;
    const uint32_t tbits = (prefix & 0x80000000u) ? (prefix & 0x7fffffffu) : ~prefix;

    if (E != R) {
        // rare: find global index of the 0-based rank-R element equal to T
        __shared__ uint32_t wcnt[16];
        const float T = __uint_as_float(tbits);
        if (tid == 0) sRun = 0;
        __syncthreads();
        const float* sc = scores + (size_t)b * NPTS;
        for (int base = 0; base < NPTS; base += 1024) {
            const uint32_t r0 = sRun;
            if (r0 > R) break;
            const int i = base + tid;
            const bool eq = (i < NPTS) && (sc[i] == T);
            const unsigned long long mask = __ballot(eq);
            if (lane == 0) wcnt[w] = (uint32_t)__popcll(mask);
            __syncthreads();
            uint32_t before = 0, total = 0;
            for (int ww = 0; ww < 16; ++ww) {
                const uint32_t c = wcnt[ww];
                if (ww < w) before += c;
                total += c;
            }
            if (eq) {
                const uint32_t rank = r0 + before +
                    (uint32_t)__popcll(mask & ((1ull << lane) - 1ull));
                if (rank == R) sIstar = (uint32_t)i;
            }
            __syncthreads();
            if (tid == 0) sRun = r0 + total;
            __syncthreads();
        }
        __syncthreads();
    }
    if (tid == 0) {
        uint32_t* st = ws + STATE_OFF + b * 2;
        st[0] = tbits;   // threshold T as float bits
        st[1] = sIstar;  // ties: s==T taken iff idx < Istar (NPTS when all taken)
    }
}

// ---------- exact (numpy-bit-identical) gt check for one point ----------
__device__ __noinline__ bool exact_gt(float px, float py, float pz,
                                      const float* __restrict__ C) {
    bool hit = false;
#pragma unroll 1
    for (int k = 0; k < NBOX; ++k) {
        float dx = px - C[3 * k + 0];
        float dy = py - C[3 * k + 1];
        float dz = pz - C[3 * k + 2];
        float d2 = __fadd_rn(__fadd_rn(__fmul_rn(dx, dx), __fmul_rn(dy, dy)),
                             __fmul_rn(dz, dz));
        if (__fsqrt_rn(d2) < THRF) hit = true;
    }
    return hit;
}

// ---------- K2: gt mask + prune mask + losses ----------
__global__ __launch_bounds__(256) void main_k(const float* __restrict__ scores,
                                              const float* __restrict__ points,
                                              const float* __restrict__ ctrs,
                                              const uint32_t* __restrict__ ws,
                                              float* __restrict__ out) {
    const int b = blockIdx.y;
    const uint32_t* st = ws + STATE_OFF + b * 2;
    const float T = __uint_as_float(st[0]);
    const uint32_t Istar = st[1];

    const int p0 = blockIdx.x * 1024 + threadIdx.x * 4;
    if (p0 >= NPTS) return;

    const float* P = points + ((size_t)b * NPTS + p0) * 3;
    const float4 a = *reinterpret_cast<const float4*>(P);
    const float4 c4 = *reinterpret_cast<const float4*>(P + 4);
    const float4 e = *reinterpret_cast<const float4*>(P + 8);
    const float px[4] = {a.x, a.w, c4.z, e.y};
    const float py[4] = {a.y, c4.x, c4.w, e.z};
    const float pz[4] = {a.z, c4.y, e.x, e.w};
    // d^2 = p.p + (c.c - 2 p.c); min commutes with +p.p (per-point constant)
    float m2[4] = {1e30f, 1e30f, 1e30f, 1e30f};

    const float* C = ctrs + b * NBOX * 3;
#pragma unroll 16
    for (int k = 0; k < NBOX; ++k) {
        const float cx = C[3 * k + 0];
        const float cy = C[3 * k + 1];
        const float cz = C[3 * k + 2];
        const float cc = fmaf(cx, cx, fmaf(cy, cy, cz * cz));
        const float m2x = -2.0f * cx, m2y = -2.0f * cy, m2z = -2.0f * cz;
#pragma unroll
        for (int j = 0; j < 4; ++j) {
            const float t = fmaf(m2x, px[j], fmaf(m2y, py[j], fmaf(m2z, pz[j], cc)));
            m2[j] = fminf(m2[j], t);
        }
    }

    const float4 sv = *reinterpret_cast<const float4*>(scores + (size_t)b * NPTS + p0);
    const float s[4] = {sv.x, sv.y, sv.z, sv.w};
    float pr[4], ls[4];
#pragma unroll
    for (int j = 0; j < 4; ++j) {
        const float pp = fmaf(px[j], px[j], fmaf(py[j], py[j], pz[j] * pz[j]));
        const float m = pp + m2[j];
        bool gt;
        if (m < C_LO) gt = true;
        else if (m >= C_HI) gt = false;
        else gt = exact_gt(px[j], py[j], pz[j], C);  // rare boundary band
        const bool sm = (s[j] > T) || (s[j] == T && (uint32_t)(p0 + j) < Istar);
        pr[j] = (gt || sm) ? 1.0f : 0.0f;
        const float x = gt ? -s[j] : s[j];
        // fast softplus: tolerance is bf16-level (9.4e-2); hw exp/log err ~1e-6
        ls[j] = fmaxf(x, 0.0f) + __logf(1.0f + __expf(-fabsf(s[j])));
    }
    float* o0 = out + (size_t)b * NPTS + p0;
    float* o1 = out + (size_t)BB * NPTS + (size_t)b * NPTS + p0;
    *reinterpret_cast<float4*>(o0) = make_float4(pr[0], pr[1], pr[2], pr[3]);
    *reinterpret_cast<float4*>(o1) = make_float4(ls[0], ls[1], ls[2], ls[3]);
}

extern "C" void kernel_launch(void* const* d_in, const int* in_sizes, int n_in,
                              void* d_out, int out_size, void* d_ws, size_t ws_size,
                              hipStream_t stream) {
    const float* scores = (const float*)d_in[0];
    const float* points = (const float*)d_in[1];
    const float* ctrs   = (const float*)d_in[2];
    float* out = (float*)d_out;
    uint32_t* ws = (uint32_t*)d_ws;

    select_k<<<BB, 1024, 0, stream>>>(scores, ws);
    const dim3 gridP(98, BB);
    main_k<<<gridP, 256, 0, stream>>>(scores, points, ctrs, ws, out);
}

// Round 9
// 47.839 us; speedup vs baseline: 4.0269x; 1.5321x over previous
//
#include <hip/hip_runtime.h>
#include <hip/hip_bf16.h>
#include <stdint.h>

// Problem constants
#define BB 16
#define NPTS 100000
#define NBOX 64
#define KTOP 2048
#define THRF 0.2f            // (float)(8*0.01*2.5)
// band around 0.2^2 for exact-path fallback; fast path error bound ~5e-6
#define C_LO 0.039984f
#define C_HI 0.040016f

#define LIST_CAP 4096        // speculative candidates ~2278 +/- 47 (>=38 sigma margin)
#define NF4 (NPTS / 4)       // 25000 float4s per batch
#define CUT 0xC0000000u      // fmap(2.0f): speculative compaction cut (score >= 2.0)

// Workspace: only BB*2 words {T_bits, Istar}; written by K1, read by K2.
#define STATE_OFF 0

__device__ __forceinline__ uint32_t fmap(float f) {
    uint32_t b = __float_as_uint(f);
    return (b & 0x80000000u) ? ~b : (b | 0x80000000u);
}

// ---------- K1: one block per batch, single-pass top-K selection ----------
__global__ __launch_bounds__(1024) void select_k(const float* __restrict__ scores,
                                                 uint32_t* __restrict__ ws) {
    const int b = blockIdx.x, tid = threadIdx.x, w = tid >> 6, lane = tid & 63;
    __shared__ uint32_t h[16][257];    // lane-spread hist copies (copy=lane&15, bank-offset 257)
    __shared__ uint32_t hist[256], excl[256];
    __shared__ uint32_t list[LIST_CAP];
    __shared__ uint32_t sBin, sKrem, sE, sTot, sIstar, sRun, lcnt;

    for (int i = tid; i < 16 * 257; i += 1024) (&h[0][0])[i] = 0;
    if (tid == 0) { sIstar = NPTS; lcnt = 0; }
    __syncthreads();

    const float4* sc4 = reinterpret_cast<const float4*>(scores + (size_t)b * NPTS);
    uint32_t* mh = h[lane & 15];

    // ---- merged pass: histogram + speculative compaction (scores read ONCE) ----
    {
        int i4 = tid;
#pragma unroll 1
        for (int it = 0; it < 8; ++it, i4 += 3072) {
            const float4 v0 = sc4[i4];
            const float4 v1 = sc4[i4 + 1024];
            const float4 v2 = sc4[i4 + 2048];
            const uint32_t u[12] = {fmap(v0.x), fmap(v0.y), fmap(v0.z), fmap(v0.w),
                                    fmap(v1.x), fmap(v1.y), fmap(v1.z), fmap(v1.w),
                                    fmap(v2.x), fmap(v2.y), fmap(v2.z), fmap(v2.w)};
#pragma unroll
            for (int j = 0; j < 12; ++j) {
                atomicAdd(&mh[u[j] >> 24], 1u);
                if (u[j] >= CUT) {  // ~2.3% of elements
                    const uint32_t pos = atomicAdd(&lcnt, 1u);
                    if (pos < LIST_CAP) list[pos] = u[j];
                }
            }
        }
        if (i4 < NF4) {  // tail: 424 float4s
            const float4 v = sc4[i4];
            const uint32_t u[4] = {fmap(v.x), fmap(v.y), fmap(v.z), fmap(v.w)};
#pragma unroll
            for (int j = 0; j < 4; ++j) {
                atomicAdd(&mh[u[j] >> 24], 1u);
                if (u[j] >= CUT) {
                    const uint32_t pos = atomicAdd(&lcnt, 1u);
                    if (pos < LIST_CAP) list[pos] = u[j];
                }
            }
        }
    }
    __syncthreads();
    if (tid < 256) {  // reduce 16 copies; banks (j+tid)%32 -> 2-way alias (free)
        uint32_t acc = 0;
#pragma unroll
        for (int j = 0; j < 16; ++j) acc += h[j][tid];
        hist[tid] = acc;
    }
    __syncthreads();

    // ---- MSB bin pick: wave-0 exclusive prefix + unique-interval select ----
    if (tid < 64) {
        const uint32_t v0 = hist[4*tid], v1 = hist[4*tid+1], v2 = hist[4*tid+2], v3 = hist[4*tid+3];
        const uint32_t lt = v0 + v1 + v2 + v3;
        uint32_t x = lt;
#pragma unroll
        for (int off = 1; off < 64; off <<= 1) {
            const uint32_t y = __shfl_up(x, off);
            if (lane >= off) x += y;
        }
        const uint32_t ex = x - lt;
        excl[4*tid] = ex; excl[4*tid+1] = ex + v0;
        excl[4*tid+2] = ex + v0 + v1; excl[4*tid+3] = ex + v0 + v1 + v2;
        if (tid == 63) sTot = x;
    }
    __syncthreads();
    if (tid < 256) {
        const uint32_t total = sTot, lim = total - KTOP;
        const uint32_t pe = excl[tid];
        const uint32_t pe1 = (tid == 255) ? total : excl[tid + 1];
        if (pe <= lim && pe1 > lim) {  // unique interval containing lim
            sBin = (uint32_t)tid;
            sKrem = KTOP - (total - pe1);
        }
    }
    __syncthreads();
    const uint32_t beta = sBin;
    uint32_t prefix = beta << 24;
    uint32_t cnt;

    // speculative list valid iff beta-bin values all >= CUT and no overflow
    const bool spec = (beta >= (CUT >> 24)) && (lcnt <= LIST_CAP);
    if (spec) {
        cnt = lcnt;
    } else {
        // corrective exact-bin re-scan (never taken for N(0,1) inputs)
        __syncthreads();
        if (tid == 0) lcnt = 0;
        __syncthreads();
        for (int i4 = tid; i4 < NF4; i4 += 1024) {
            const float4 v = sc4[i4];
            const uint32_t u[4] = {fmap(v.x), fmap(v.y), fmap(v.z), fmap(v.w)};
#pragma unroll
            for (int j = 0; j < 4; ++j) {
                if ((u[j] >> 24) == beta) {
                    const uint32_t pos = atomicAdd(&lcnt, 1u);
                    if (pos < LIST_CAP) list[pos] = u[j];
                }
            }
        }
        __syncthreads();
        cnt = lcnt;
    }
    if (cnt > LIST_CAP) cnt = LIST_CAP;

    // ---- 3 radix passes over the candidate list (prefix-filtered superset OK) ----
#pragma unroll 1
    for (int shift = 16; shift >= 0; shift -= 8) {
        __syncthreads();
        if (tid < 256) hist[tid] = 0;
        __syncthreads();
        const uint32_t hi8 = prefix >> (shift + 8);
        for (uint32_t i = tid; i < cnt; i += 1024) {
            const uint32_t uu = list[i];
            if ((uu >> (shift + 8)) == hi8)
                atomicAdd(&hist[(uu >> shift) & 255u], 1u);
        }
        __syncthreads();
        if (tid < 64) {
            const uint32_t v0 = hist[4*tid], v1 = hist[4*tid+1], v2 = hist[4*tid+2], v3 = hist[4*tid+3];
            const uint32_t lt = v0 + v1 + v2 + v3;
            uint32_t x = lt;
#pragma unroll
            for (int off = 1; off < 64; off <<= 1) {
                const uint32_t y = __shfl_up(x, off);
                if (lane >= off) x += y;
            }
            const uint32_t ex = x - lt;
            excl[4*tid] = ex; excl[4*tid+1] = ex + v0;
            excl[4*tid+2] = ex + v0 + v1; excl[4*tid+3] = ex + v0 + v1 + v2;
            if (tid == 63) sTot = x;
        }
        __syncthreads();
        if (tid < 256) {
            const uint32_t target = sKrem;
            const uint32_t total = sTot, lim = total - target;
            const uint32_t pe = excl[tid];
            const uint32_t pe1 = (tid == 255) ? total : excl[tid + 1];
            if (pe <= lim && pe1 > lim) {
                sBin = (uint32_t)tid;
                sKrem = target - (total - pe1);
                if (shift == 0) sE = pe1 - pe;
            }
        }
        __syncthreads();
        prefix |= sBin << shift;
    }

    const uint32_t R = sKrem, E = sE;
    const uint32_t tbits = (prefix & 0x80000000u) ? (prefix & 0x7fffffffu) : ~prefix;

    if (E != R) {
        // rare: find global index of the 0-based rank-R element equal to T
        __shared__ uint32_t wcnt[16];
        const float T = __uint_as_float(tbits);
        if (tid == 0) sRun = 0;
        __syncthreads();
        const float* sc = scores + (size_t)b * NPTS;
        for (int base = 0; base < NPTS; base += 1024) {
            const uint32_t r0 = sRun;
            if (r0 > R) break;
            const int i = base + tid;
            const bool eq = (i < NPTS) && (sc[i] == T);
            const unsigned long long mask = __ballot(eq);
            if (lane == 0) wcnt[w] = (uint32_t)__popcll(mask);
            __syncthreads();
            uint32_t before = 0, total = 0;
            for (int ww = 0; ww < 16; ++ww) {
                const uint32_t c = wcnt[ww];
                if (ww < w) before += c;
                total += c;
            }
            if (eq) {
                const uint32_t rank = r0 + before +
                    (uint32_t)__popcll(mask & ((1ull << lane) - 1ull));
                if (rank == R) sIstar = (uint32_t)i;
            }
            __syncthreads();
            if (tid == 0) sRun = r0 + total;
            __syncthreads();
        }
        __syncthreads();
    }
    if (tid == 0) {
        uint32_t* st = ws + STATE_OFF + b * 2;
        st[0] = tbits;   // threshold T as float bits
        st[1] = sIstar;  // ties: s==T taken iff idx < Istar (NPTS when all taken)
    }
}

// ---------- exact (numpy-bit-identical) gt check for one point ----------
__device__ __noinline__ bool exact_gt(float px, float py, float pz,
                                      const float* __restrict__ C) {
    bool hit = false;
#pragma unroll 1
    for (int k = 0; k < NBOX; ++k) {
        float dx = px - C[3 * k + 0];
        float dy = py - C[3 * k + 1];
        float dz = pz - C[3 * k + 2];
        float d2 = __fadd_rn(__fadd_rn(__fmul_rn(dx, dx), __fmul_rn(dy, dy)),
                             __fmul_rn(dz, dz));
        if (__fsqrt_rn(d2) < THRF) hit = true;
    }
    return hit;
}

// ---------- K2: gt mask + prune mask + losses ----------
__global__ __launch_bounds__(256) void main_k(const float* __restrict__ scores,
                                              const float* __restrict__ points,
                                              const float* __restrict__ ctrs,
                                              const uint32_t* __restrict__ ws,
                                              float* __restrict__ out) {
    const int b = blockIdx.y;
    const uint32_t* st = ws + STATE_OFF + b * 2;
    const float T = __uint_as_float(st[0]);
    const uint32_t Istar = st[1];

    const int p0 = blockIdx.x * 1024 + threadIdx.x * 4;
    if (p0 >= NPTS) return;

    const float* P = points + ((size_t)b * NPTS + p0) * 3;
    const float4 a = *reinterpret_cast<const float4*>(P);
    const float4 c4 = *reinterpret_cast<const float4*>(P + 4);
    const float4 e = *reinterpret_cast<const float4*>(P + 8);
    const float px[4] = {a.x, a.w, c4.z, e.y};
    const float py[4] = {a.y, c4.x, c4.w, e.z};
    const float pz[4] = {a.z, c4.y, e.x, e.w};
    // d^2 = p.p + (c.c - 2 p.c); min commutes with +p.p (per-point constant)
    float m2[4] = {1e30f, 1e30f, 1e30f, 1e30f};

    const float* C = ctrs + b * NBOX * 3;
#pragma unroll 16
    for (int k = 0; k < NBOX; ++k) {
        const float cx = C[3 * k + 0];
        const float cy = C[3 * k + 1];
        const float cz = C[3 * k + 2];
        const float cc = fmaf(cx, cx, fmaf(cy, cy, cz * cz));
        const float m2x = -2.0f * cx, m2y = -2.0f * cy, m2z = -2.0f * cz;
#pragma unroll
        for (int j = 0; j < 4; ++j) {
            const float t = fmaf(m2x, px[j], fmaf(m2y, py[j], fmaf(m2z, pz[j], cc)));
            m2[j] = fminf(m2[j], t);
        }
    }

    const float4 sv = *reinterpret_cast<const float4*>(scores + (size_t)b * NPTS + p0);
    const float s[4] = {sv.x, sv.y, sv.z, sv.w};
    float pr[4], ls[4];
#pragma unroll
    for (int j = 0; j < 4; ++j) {
        const float pp = fmaf(px[j], px[j], fmaf(py[j], py[j], pz[j] * pz[j]));
        const float m = pp + m2[j];
        bool gt;
        if (m < C_LO) gt = true;
        else if (m >= C_HI) gt = false;
        else gt = exact_gt(px[j], py[j], pz[j], C);  // rare boundary band
        const bool sm = (s[j] > T) || (s[j] == T && (uint32_t)(p0 + j) < Istar);
        pr[j] = (gt || sm) ? 1.0f : 0.0f;
        const float x = gt ? -s[j] : s[j];
        // fast softplus: tolerance is bf16-level (9.4e-2); hw exp/log err ~1e-6
        ls[j] = fmaxf(x, 0.0f) + __logf(1.0f + __expf(-fabsf(s[j])));
    }
    float* o0 = out + (size_t)b * NPTS + p0;
    float* o1 = out + (size_t)BB * NPTS + (size_t)b * NPTS + p0;
    *reinterpret_cast<float4*>(o0) = make_float4(pr[0], pr[1], pr[2], pr[3]);
    *reinterpret_cast<float4*>(o1) = make_float4(ls[0], ls[1], ls[2], ls[3]);
}

extern "C" void kernel_launch(void* const* d_in, const int* in_sizes, int n_in,
                              void* d_out, int out_size, void* d_ws, size_t ws_size,
                              hipStream_t stream) {
    const float* scores = (const float*)d_in[0];
    const float* points = (const float*)d_in[1];
    const float* ctrs   = (const float*)d_in[2];
    float* out = (float*)d_out;
    uint32_t* ws = (uint32_t*)d_ws;

    select_k<<<BB, 1024, 0, stream>>>(scores, ws);
    const dim3 gridP(98, BB);
    main_k<<<gridP, 256, 0, stream>>>(scores, points, ctrs, ws, out);
}